// Round 7
// baseline (357.224 us; speedup 1.0000x reference)
//
#include <hip/hip_runtime.h>

#define BB 32
#define TT 1024
#define ENCD 1024
#define DECD 1024
#define MELD 80
#define KTOT (MELD + ENCD + DECD)   // 2128
#define NZ (4 * DECD)               // 4096

// ---- static device scratch (no d_ws dependence) ----
__device__ float g_scores[BB * TT];
__device__ float g_attn[BB * TT];
__device__ float g_ctx[BB * ENCD];     // zeroed by k_zero
__device__ float g_z[BB * NZ];         // zeroed by k_zero
__device__ float g_hn[BB * DECD];

__device__ __forceinline__ float tanh_fast(float x) {
    float e = __expf(2.f * x);
    return 1.f - 2.f / (e + 1.f);   // exact +-1 limits
}
__device__ __forceinline__ float sigmoid_fast(float x) {
    return 1.f / (1.f + __expf(-x));
}

// ---------------------------------------------------------------------------
__global__ __launch_bounds__(256) void k_zero() {
    int i = blockIdx.x * 256 + threadIdx.x;   // grid 640 -> 163840
    if (i < BB * ENCD) g_ctx[i] = 0.f;
    if (i < BB * NZ)   g_z[i]   = 0.f;
}

// ---------------------------------------------------------------------------
// K1: scores[b,t] = sum_d scale[d] * tanh(h[b,d] + enc[b,t,d])
// one wave per (b,t); each lane owns 16 contiguous d (4x float4).
// ---------------------------------------------------------------------------
__global__ __launch_bounds__(256) void k_scores(const float* __restrict__ enc,
                                                const float* __restrict__ h,
                                                const float* __restrict__ scale) {
    int w = blockIdx.x * 4 + (threadIdx.x >> 6);   // b*1024 + t
    int lane = threadIdx.x & 63;
    int b = w >> 10;
    const float4* ep = (const float4*)(enc + (size_t)w * ENCD + lane * 16);
    const float4* hp = (const float4*)(h + (size_t)b * DECD + lane * 16);
    const float4* sp = (const float4*)(scale + lane * 16);
    float sum = 0.f;
#pragma unroll
    for (int i = 0; i < 4; i++) {
        float4 e = ep[i], hv = hp[i], s = sp[i];
        sum += s.x * tanh_fast(hv.x + e.x);
        sum += s.y * tanh_fast(hv.y + e.y);
        sum += s.z * tanh_fast(hv.z + e.z);
        sum += s.w * tanh_fast(hv.w + e.w);
    }
#pragma unroll
    for (int off = 32; off > 0; off >>= 1) sum += __shfl_down(sum, off, 64);
    if (lane == 0) g_scores[w] = sum;
}

// ---------------------------------------------------------------------------
// K2: softmax over t per batch.
// ---------------------------------------------------------------------------
__global__ __launch_bounds__(256) void k_softmax() {
    int b = blockIdx.x, tid = threadIdx.x;
    __shared__ float red[4];
    float v[4];
#pragma unroll
    for (int i = 0; i < 4; i++) v[i] = g_scores[b * TT + tid + i * 256];
    float m = fmaxf(fmaxf(v[0], v[1]), fmaxf(v[2], v[3]));
#pragma unroll
    for (int off = 32; off > 0; off >>= 1) m = fmaxf(m, __shfl_down(m, off, 64));
    if ((tid & 63) == 0) red[tid >> 6] = m;
    __syncthreads();
    m = fmaxf(fmaxf(red[0], red[1]), fmaxf(red[2], red[3]));
    __syncthreads();
    float e[4];
    float s = 0.f;
#pragma unroll
    for (int i = 0; i < 4; i++) { e[i] = __expf(v[i] - m); s += e[i]; }
#pragma unroll
    for (int off = 32; off > 0; off >>= 1) s += __shfl_down(s, off, 64);
    if ((tid & 63) == 0) red[tid >> 6] = s;
    __syncthreads();
    s = red[0] + red[1] + red[2] + red[3];
    float inv = 1.f / s;
#pragma unroll
    for (int i = 0; i < 4; i++) g_attn[b * TT + tid + i * 256] = e[i] * inv;
}

// ---------------------------------------------------------------------------
// K3: context[b,d] = sum_t attn[b,t] * enc[b,t,d]
// grid (32,1,8); thread owns 4 d (float4), loops 128 t; atomicAdd into g_ctx.
// ---------------------------------------------------------------------------
__global__ __launch_bounds__(256) void k_context(const float* __restrict__ enc) {
    int b = blockIdx.x, tt = blockIdx.z, tid = threadIdx.x;
    __shared__ float la[128];
    if (tid < 128) la[tid] = g_attn[b * TT + tt * 128 + tid];
    __syncthreads();
    int d0 = tid * 4;
    const float4* ep = (const float4*)(enc + ((size_t)b * TT + tt * 128) * ENCD + d0);
    float ax = 0.f, ay = 0.f, az = 0.f, aw = 0.f;
#pragma unroll 4
    for (int t = 0; t < 128; t++) {
        float4 e = ep[(size_t)t * (ENCD / 4)];
        float w = la[t];
        ax += w * e.x; ay += w * e.y; az += w * e.z; aw += w * e.w;
    }
    atomicAdd(&g_ctx[b * ENCD + d0 + 0], ax);
    atomicAdd(&g_ctx[b * ENCD + d0 + 1], ay);
    atomicAdd(&g_ctx[b * ENCD + d0 + 2], az);
    atomicAdd(&g_ctx[b * ENCD + d0 + 3], aw);
}

// ---------------------------------------------------------------------------
// K4: z[b,j] = concat(pm,ctx,h)[b,:] @ vstack(kernel,rec_kernel)[:,j]
// 512 blocks = 16 j-tiles (256 cols) x 32 k-chunks (67 rows).
// x staged in LDS for all 32 batches (weights read exactly once);
// fp32 atomicAdd partials into g_z.
// ---------------------------------------------------------------------------
__global__ __launch_bounds__(256) void k_zmm(const float* __restrict__ pm,
                                             const float* __restrict__ h,
                                             const float* __restrict__ kern,
                                             const float* __restrict__ reck) {
    __shared__ float xs[67 * 32];
    int jt = blockIdx.x & 15, kc = blockIdx.x >> 4;
    int k0 = kc * 67;
    int kcount = min(67, KTOT - k0);
    int tid = threadIdx.x;
    for (int idx = tid; idx < kcount * 32; idx += 256) {
        int kk = idx >> 5, b = idx & 31;
        int k = k0 + kk;
        float v;
        if (k < MELD)             v = pm[b * MELD + k];
        else if (k < MELD + ENCD) v = g_ctx[b * ENCD + (k - MELD)];
        else                      v = h[b * DECD + (k - MELD - ENCD)];
        xs[idx] = v;
    }
    __syncthreads();
    int j = jt * 256 + tid;
    float acc[32];
#pragma unroll
    for (int b = 0; b < 32; b++) acc[b] = 0.f;
    for (int kk = 0; kk < kcount; kk++) {
        int k = k0 + kk;
        float w = (k < MELD + ENCD) ? kern[(size_t)k * NZ + j]
                                    : reck[(size_t)(k - MELD - ENCD) * NZ + j];
        const float* xr = xs + kk * 32;
#pragma unroll
        for (int b = 0; b < 32; b++) acc[b] = fmaf(xr[b], w, acc[b]);
    }
#pragma unroll
    for (int b = 0; b < 32; b++) atomicAdd(&g_z[(size_t)b * NZ + j], acc[b]);
}

// ---------------------------------------------------------------------------
// K5: gates -> c_new, h_new (fp32 out). out: mel[0,2560) h[2560,35328) c[35328,68096)
// ---------------------------------------------------------------------------
__global__ __launch_bounds__(256) void k_gates(const float* __restrict__ bias,
                                               const float* __restrict__ c,
                                               float* __restrict__ out) {
    int idx = blockIdx.x * 256 + threadIdx.x;   // 32768
    int b = idx >> 10, jd = idx & 1023;
    const float* zb = g_z + (size_t)b * NZ;
    float zi = zb[jd]        + bias[jd];
    float zf = zb[1024 + jd] + bias[1024 + jd];
    float zg = zb[2048 + jd] + bias[2048 + jd];
    float zo = zb[3072 + jd] + bias[3072 + jd];
    float cn = sigmoid_fast(zf) * c[idx] + sigmoid_fast(zi) * tanh_fast(zg);
    float hn = sigmoid_fast(zo) * tanh_fast(cn);
    g_hn[idx] = hn;
    out[2560 + idx] = hn;
    out[2560 + 32768 + idx] = cn;
}

// ---------------------------------------------------------------------------
// K6: mel[b,m] = h_new[b,:] @ proj_w[:,m] + proj_b[m]
// ---------------------------------------------------------------------------
__global__ __launch_bounds__(256) void k_proj(const float* __restrict__ pw,
                                              const float* __restrict__ pb,
                                              float* __restrict__ out) {
    __shared__ float lh[1024];
    int b = blockIdx.x, tid = threadIdx.x;
    for (int i = tid; i < 1024; i += 256) lh[i] = g_hn[b * 1024 + i];
    __syncthreads();
    if (tid < MELD) {
        float acc = pb[tid];
#pragma unroll 8
        for (int d = 0; d < 1024; d++) acc = fmaf(lh[d], pw[d * MELD + tid], acc);
        out[b * MELD + tid] = acc;
    }
}

extern "C" void kernel_launch(void* const* d_in, const int* in_sizes, int n_in,
                              void* d_out, int out_size, void* d_ws, size_t ws_size,
                              hipStream_t stream) {
    // dict order, fp32 per the reference (harness rule: dtype follows reference)
    const float* pm   = (const float*)d_in[0];   // prev_mel_frame [32,80]
    const float* enc  = (const float*)d_in[1];   // encoder_outputs [32,1024,1024]
    const float* h    = (const float*)d_in[2];   // h [32,1024]
    const float* c    = (const float*)d_in[3];   // c [32,1024]
    const float* asc  = (const float*)d_in[4];   // attn_scale [1024]
    const float* kern = (const float*)d_in[5];   // kernel [1104,4096]
    const float* reck = (const float*)d_in[6];   // rec_kernel [1024,4096]
    const float* bias = (const float*)d_in[7];   // bias [4096]
    const float* pw   = (const float*)d_in[8];   // proj_w [1024,80]
    const float* pb   = (const float*)d_in[9];   // proj_b [80]
    float* out = (float*)d_out;                  // fp32 output: mel | h_new | c_new

    k_zero   <<<640, 256, 0, stream>>>();
    k_scores <<<8192, 256, 0, stream>>>(enc, h, asc);
    k_softmax<<<32, 256, 0, stream>>>();
    k_context<<<dim3(32, 1, 8), 256, 0, stream>>>(enc);
    k_zmm    <<<512, 256, 0, stream>>>(pm, h, kern, reck);
    k_gates  <<<128, 256, 0, stream>>>(bias, c, out);
    k_proj   <<<32, 256, 0, stream>>>(pw, pb, out);
}

// Round 8
// 348.947 us; speedup vs baseline: 1.0237x; 1.0237x over previous
//
#include <hip/hip_runtime.h>

#define BB 32
#define TT 1024
#define ENCD 1024
#define DECD 1024
#define MELD 80
#define KTOT (MELD + ENCD + DECD)   // 2128
#define NZ (4 * DECD)               // 4096
#define KC 16                       // k-chunks in zmm
#define KCH 133                     // 16*133 = 2128

// ---- static device scratch ----
__device__ float g_scores[BB * TT];
__device__ float g_cp[8 * BB * ENCD];    // context partials [tt][b][d]
__device__ float g_ctx[BB * ENCD];
__device__ float g_zp[KC * BB * NZ];     // z partials [kc][b][j]
__device__ float g_hn[BB * DECD];

__device__ __forceinline__ float tanh_fast(float x) {
    // 1 - 2/(e+1): exact +-1 limits even with fast division (rcp(inf)=0)
    return 1.f - __fdividef(2.f, __expf(2.f * x) + 1.f);
}
__device__ __forceinline__ float sigmoid_fast(float x) {
    return __fdividef(1.f, 1.f + __expf(-x));
}

// ---------------------------------------------------------------------------
// K1: scores[b,t] = sum_d scale[d] * tanh(h[b,d] + enc[b,t,d])
// one wave per (b,t); float4 loads, lanes contiguous (1KB/instr).
// ---------------------------------------------------------------------------
__global__ __launch_bounds__(256) void k_scores(const float* __restrict__ enc,
                                                const float* __restrict__ h,
                                                const float* __restrict__ scale) {
    int w = blockIdx.x * 4 + (threadIdx.x >> 6);   // b*1024 + t
    int lane = threadIdx.x & 63;
    int b = w >> 10;
    const float4* ep = (const float4*)(enc + (size_t)w * ENCD);
    const float4* hp = (const float4*)(h + (size_t)b * DECD);
    const float4* sp = (const float4*)scale;
    float sum = 0.f;
#pragma unroll
    for (int j = 0; j < 4; j++) {
        int i = lane + j * 64;
        float4 e = ep[i], hv = hp[i], s = sp[i];
        sum += s.x * tanh_fast(hv.x + e.x);
        sum += s.y * tanh_fast(hv.y + e.y);
        sum += s.z * tanh_fast(hv.z + e.z);
        sum += s.w * tanh_fast(hv.w + e.w);
    }
#pragma unroll
    for (int off = 32; off > 0; off >>= 1) sum += __shfl_down(sum, off, 64);
    if (lane == 0) g_scores[w] = sum;
}

// ---------------------------------------------------------------------------
// K2: fused softmax + context partials.
// grid (b=32, dt=4, tt=8), 256 threads. Each block re-derives (m, s) from
// scores[b,:] (L2-hot, deterministic across blocks), builds its 128-t attn
// tile in LDS, accumulates ctx partial for its 256 d, writes g_cp[tt][b][d].
// No atomics, no pre-zeroing.
// ---------------------------------------------------------------------------
__global__ __launch_bounds__(256) void k_context(const float* __restrict__ enc) {
    int b = blockIdx.x, dt = blockIdx.y, tt = blockIdx.z, tid = threadIdx.x;
    __shared__ float red[4];
    __shared__ float la[128];
    float v[4];
#pragma unroll
    for (int i = 0; i < 4; i++) v[i] = g_scores[b * TT + tid + i * 256];
    float m = fmaxf(fmaxf(v[0], v[1]), fmaxf(v[2], v[3]));
#pragma unroll
    for (int off = 32; off > 0; off >>= 1) m = fmaxf(m, __shfl_down(m, off, 64));
    if ((tid & 63) == 0) red[tid >> 6] = m;
    __syncthreads();
    m = fmaxf(fmaxf(red[0], red[1]), fmaxf(red[2], red[3]));
    __syncthreads();
    float s = 0.f;
#pragma unroll
    for (int i = 0; i < 4; i++) s += __expf(v[i] - m);
#pragma unroll
    for (int off = 32; off > 0; off >>= 1) s += __shfl_down(s, off, 64);
    if ((tid & 63) == 0) red[tid >> 6] = s;
    __syncthreads();
    s = red[0] + red[1] + red[2] + red[3];
    float inv = __fdividef(1.f, s);
    if (tid < 128) la[tid] = __expf(g_scores[b * TT + tt * 128 + tid] - m) * inv;
    __syncthreads();

    int d = dt * 256 + tid;
    const float* e0 = enc + ((size_t)b * TT + tt * 128) * ENCD + d;
    float a = 0.f;
#pragma unroll 8
    for (int t = 0; t < 128; t++) a = fmaf(la[t], e0[(size_t)t * ENCD], a);
    g_cp[((size_t)tt * BB + b) * ENCD + d] = a;
}

// ---------------------------------------------------------------------------
// K3: ctx[b,d] = sum_tt g_cp[tt][b][d]  (coalesced 8-way reduce, 1 MB)
// ---------------------------------------------------------------------------
__global__ __launch_bounds__(256) void k_ctxsum() {
    int i = blockIdx.x * 256 + threadIdx.x;   // grid 128 -> 32768
    float a = 0.f;
#pragma unroll
    for (int tt = 0; tt < 8; tt++) a += g_cp[tt * (BB * ENCD) + i];
    g_ctx[i] = a;
}

// ---------------------------------------------------------------------------
// K4: z partials. grid 256 = 16 jt x 16 kc, 256 threads.
// x staged in LDS for all 32 batches (weights read exactly once).
// Plain stores to g_zp[kc][b][j] (b-loop coalesced). No atomics.
// ---------------------------------------------------------------------------
__global__ __launch_bounds__(256) void k_zmm(const float* __restrict__ pm,
                                             const float* __restrict__ h,
                                             const float* __restrict__ kern,
                                             const float* __restrict__ reck) {
    __shared__ float xs[KCH * 32];
    int jt = blockIdx.x & 15, kc = blockIdx.x >> 4;
    int k0 = kc * KCH;
    int tid = threadIdx.x;
    for (int idx = tid; idx < KCH * 32; idx += 256) {
        int kk = idx >> 5, b = idx & 31;
        int k = k0 + kk;
        float v;
        if (k < MELD)             v = pm[b * MELD + k];
        else if (k < MELD + ENCD) v = g_ctx[b * ENCD + (k - MELD)];
        else                      v = h[b * DECD + (k - MELD - ENCD)];
        xs[idx] = v;
    }
    __syncthreads();
    int j = jt * 256 + tid;
    float acc[32];
#pragma unroll
    for (int b = 0; b < 32; b++) acc[b] = 0.f;
    for (int kk = 0; kk < KCH; kk++) {
        int k = k0 + kk;
        float w = (k < MELD + ENCD) ? kern[(size_t)k * NZ + j]
                                    : reck[(size_t)(k - MELD - ENCD) * NZ + j];
        const float* xr = xs + kk * 32;
#pragma unroll
        for (int b = 0; b < 32; b++) acc[b] = fmaf(xr[b], w, acc[b]);
    }
#pragma unroll
    for (int b = 0; b < 32; b++) g_zp[((size_t)kc * BB + b) * NZ + j] = acc[b];
}

// ---------------------------------------------------------------------------
// K5: sum z partials + bias, gates -> h_new/c_new (fp32 out).
// grid 128 = 32 b x 4 jq, 256 threads, one j per thread (coalesced reads).
// out: mel[0,2560) h[2560,35328) c[35328,68096)
// ---------------------------------------------------------------------------
__global__ __launch_bounds__(256) void k_gates(const float* __restrict__ bias,
                                               const float* __restrict__ c,
                                               float* __restrict__ out) {
    int b = blockIdx.x >> 2, jq = blockIdx.x & 3;
    int j = jq * 256 + threadIdx.x;
    float zi = bias[j], zf = bias[1024 + j], zg = bias[2048 + j], zo = bias[3072 + j];
#pragma unroll
    for (int kc = 0; kc < KC; kc++) {
        const float* zp = g_zp + ((size_t)kc * BB + b) * NZ;
        zi += zp[j];
        zf += zp[1024 + j];
        zg += zp[2048 + j];
        zo += zp[3072 + j];
    }
    int idx = b * 1024 + j;
    float cn = sigmoid_fast(zf) * c[idx] + sigmoid_fast(zi) * tanh_fast(zg);
    float hn = sigmoid_fast(zo) * tanh_fast(cn);
    g_hn[idx] = hn;
    out[2560 + idx] = hn;
    out[35328 + idx] = cn;
}

// ---------------------------------------------------------------------------
// K6: mel[b,m] = h_new[b,:] @ proj_w[:,m] + proj_b[m]
// grid 32; 160 active threads = 80 m x 2 d-halves, LDS combine.
// ---------------------------------------------------------------------------
__global__ __launch_bounds__(256) void k_proj(const float* __restrict__ pw,
                                              const float* __restrict__ pb,
                                              float* __restrict__ out) {
    __shared__ float lh[1024];
    __shared__ float pacc[2][MELD];
    int b = blockIdx.x, tid = threadIdx.x;
    for (int i = tid; i < 1024; i += 256) lh[i] = g_hn[b * 1024 + i];
    __syncthreads();
    int m = tid & 127;
    int g = tid >> 7;
    if (m < MELD) {
        float acc = 0.f;
        int d0 = g * 512;
#pragma unroll 8
        for (int d = d0; d < d0 + 512; d++) acc = fmaf(lh[d], pw[d * MELD + m], acc);
        pacc[g][m] = acc;
    }
    __syncthreads();
    if (tid < MELD) out[b * MELD + tid] = pacc[0][tid] + pacc[1][tid] + pb[tid];
}

extern "C" void kernel_launch(void* const* d_in, const int* in_sizes, int n_in,
                              void* d_out, int out_size, void* d_ws, size_t ws_size,
                              hipStream_t stream) {
    const float* pm   = (const float*)d_in[0];   // prev_mel_frame [32,80]
    const float* enc  = (const float*)d_in[1];   // encoder_outputs [32,1024,1024]
    const float* h    = (const float*)d_in[2];   // h [32,1024]
    const float* c    = (const float*)d_in[3];   // c [32,1024]
    const float* asc  = (const float*)d_in[4];   // attn_scale [1024]
    const float* kern = (const float*)d_in[5];   // kernel [1104,4096]
    const float* reck = (const float*)d_in[6];   // rec_kernel [1024,4096]
    const float* bias = (const float*)d_in[7];   // bias [4096]
    const float* pw   = (const float*)d_in[8];   // proj_w [1024,80]
    const float* pb   = (const float*)d_in[9];   // proj_b [80]
    float* out = (float*)d_out;                  // fp32: mel | h_new | c_new

    k_scores <<<8192, 256, 0, stream>>>(enc, h, asc);
    k_context<<<dim3(32, 4, 8), 256, 0, stream>>>(enc);
    k_ctxsum <<<128, 256, 0, stream>>>();
    k_zmm    <<<256, 256, 0, stream>>>(pm, h, kern, reck);
    k_gates  <<<128, 256, 0, stream>>>(bias, c, out);
    k_proj   <<<32, 256, 0, stream>>>(pw, pb, out);
}

// Round 9
// 300.829 us; speedup vs baseline: 1.1875x; 1.1600x over previous
//
#include <hip/hip_runtime.h>

#define BB 32
#define TT 1024
#define ENCD 1024
#define DECD 1024
#define MELD 80
#define KTOT (MELD + ENCD + DECD)   // 2128
#define NZ (4 * DECD)               // 4096
#define KCH 64                      // k-rows per zmm chunk
#define KC 34                       // ceil(2128/64); last chunk = 16 rows

// ---- static device scratch ----
__device__ float g_scores[BB * TT];
__device__ float g_cp[8 * BB * ENCD];    // context partials [tt][b][d]  (1 MB)
__device__ float g_ctx[BB * ENCD];
__device__ float g_zp[KC * BB * NZ];     // z partials [kc][b][j]        (17.8 MB)
__device__ float g_hn[BB * DECD];

__device__ __forceinline__ float tanh_fast(float x) {
    // 1 - 2/(e+1): exact +-1 limits (rcp(inf)=0)
    return 1.f - __fdividef(2.f, __expf(2.f * x) + 1.f);
}
__device__ __forceinline__ float sigmoid_fast(float x) {
    return __fdividef(1.f, 1.f + __expf(-x));
}

// ---------------------------------------------------------------------------
// K1: scores[b,t] = sum_d scale[d] * tanh(h[b,d] + enc[b,t,d])
// one wave per (b,t); float4 loads, lanes contiguous (1KB/wave-instr).
// ---------------------------------------------------------------------------
__global__ __launch_bounds__(256) void k_scores(const float* __restrict__ enc,
                                                const float* __restrict__ h,
                                                const float* __restrict__ scale) {
    int w = blockIdx.x * 4 + (threadIdx.x >> 6);   // b*1024 + t
    int lane = threadIdx.x & 63;
    int b = w >> 10;
    const float4* ep = (const float4*)(enc + (size_t)w * ENCD);
    const float4* hp = (const float4*)(h + (size_t)b * DECD);
    const float4* sp = (const float4*)scale;
    float sum = 0.f;
#pragma unroll
    for (int j = 0; j < 4; j++) {
        int i = lane + j * 64;
        float4 e = ep[i], hv = hp[i], s = sp[i];
        sum += s.x * tanh_fast(hv.x + e.x);
        sum += s.y * tanh_fast(hv.y + e.y);
        sum += s.z * tanh_fast(hv.z + e.z);
        sum += s.w * tanh_fast(hv.w + e.w);
    }
#pragma unroll
    for (int off = 32; off > 0; off >>= 1) sum += __shfl_down(sum, off, 64);
    if (lane == 0) g_scores[w] = sum;
}

// ---------------------------------------------------------------------------
// K2: fused softmax + context partials.
// grid (b=32, tt=8), 256 threads. Block re-derives (m,s) from scores[b,:]
// (L2-hot, deterministic), builds its 128-t attn tile in LDS, accumulates
// ctx partial for ALL 1024 d (float4/thread), writes g_cp[tt][b][:].
// ---------------------------------------------------------------------------
__global__ __launch_bounds__(256) void k_context(const float* __restrict__ enc) {
    int b = blockIdx.x, tt = blockIdx.y, tid = threadIdx.x;
    __shared__ float red[4];
    __shared__ float la[128];
    float v[4];
#pragma unroll
    for (int i = 0; i < 4; i++) v[i] = g_scores[b * TT + tid + i * 256];
    float m = fmaxf(fmaxf(v[0], v[1]), fmaxf(v[2], v[3]));
#pragma unroll
    for (int off = 32; off > 0; off >>= 1) m = fmaxf(m, __shfl_down(m, off, 64));
    if ((tid & 63) == 0) red[tid >> 6] = m;
    __syncthreads();
    m = fmaxf(fmaxf(red[0], red[1]), fmaxf(red[2], red[3]));
    __syncthreads();
    float s = 0.f;
#pragma unroll
    for (int i = 0; i < 4; i++) s += __expf(v[i] - m);
#pragma unroll
    for (int off = 32; off > 0; off >>= 1) s += __shfl_down(s, off, 64);
    if ((tid & 63) == 0) red[tid >> 6] = s;
    __syncthreads();
    s = red[0] + red[1] + red[2] + red[3];
    float inv = __fdividef(1.f, s);
    if (tid < 128) la[tid] = __expf(g_scores[b * TT + tt * 128 + tid] - m) * inv;
    __syncthreads();

    const float4* ep = (const float4*)(enc + ((size_t)b * TT + tt * 128) * ENCD) + tid;
    float ax = 0.f, ay = 0.f, az = 0.f, aw = 0.f;
#pragma unroll 8
    for (int t = 0; t < 128; t++) {
        float4 e = ep[(size_t)t * (ENCD / 4)];
        float w = la[t];
        ax = fmaf(w, e.x, ax); ay = fmaf(w, e.y, ay);
        az = fmaf(w, e.z, az); aw = fmaf(w, e.w, aw);
    }
    float4 r; r.x = ax; r.y = ay; r.z = az; r.w = aw;
    ((float4*)g_cp)[((size_t)tt * BB + b) * (ENCD / 4) + tid] = r;
}

// ---------------------------------------------------------------------------
// K3: ctx[b,d] = sum_tt g_cp[tt][b][d]  (coalesced 8-way reduce)
// ---------------------------------------------------------------------------
__global__ __launch_bounds__(256) void k_ctxsum() {
    int i = blockIdx.x * 256 + threadIdx.x;   // grid 128 -> 32768
    float a = 0.f;
#pragma unroll
    for (int tt = 0; tt < 8; tt++) a += g_cp[tt * (BB * ENCD) + i];
    g_ctx[i] = a;
}

// ---------------------------------------------------------------------------
// K4: z partials. grid 544 = 16 jt x 34 kc (KCH=64; last chunk 16 rows).
// x staged in LDS for all 32 batches; weight loads batched 8-wide so each
// wave keeps 8 independent global loads in flight (latency hiding).
// Plain stores to g_zp[kc][b][j]. No atomics.
// ---------------------------------------------------------------------------
__global__ __launch_bounds__(256) void k_zmm(const float* __restrict__ pm,
                                             const float* __restrict__ h,
                                             const float* __restrict__ kern,
                                             const float* __restrict__ reck) {
    __shared__ float xs[KCH * 32];
    int jt = blockIdx.x & 15, kc = blockIdx.x >> 4;
    int k0 = kc * KCH;
    int kcount = min(KCH, KTOT - k0);   // 64 or 16, both divisible by 8
    int tid = threadIdx.x;
    for (int idx = tid; idx < kcount * 32; idx += 256) {
        int kk = idx >> 5, b = idx & 31;
        int k = k0 + kk;
        float v;
        if (k < MELD)             v = pm[b * MELD + k];
        else if (k < MELD + ENCD) v = g_ctx[b * ENCD + (k - MELD)];
        else                      v = h[b * DECD + (k - MELD - ENCD)];
        xs[idx] = v;
    }
    __syncthreads();
    int j = jt * 256 + tid;
    float acc[32];
#pragma unroll
    for (int b = 0; b < 32; b++) acc[b] = 0.f;
    for (int kk0 = 0; kk0 < kcount; kk0 += 8) {
        float w[8];
#pragma unroll
        for (int i = 0; i < 8; i++) {
            int k = k0 + kk0 + i;
            w[i] = (k < MELD + ENCD) ? kern[(size_t)k * NZ + j]
                                     : reck[(size_t)(k - MELD - ENCD) * NZ + j];
        }
#pragma unroll
        for (int i = 0; i < 8; i++) {
            const float* xr = xs + (kk0 + i) * 32;
#pragma unroll
            for (int b = 0; b < 32; b++) acc[b] = fmaf(xr[b], w[i], acc[b]);
        }
    }
#pragma unroll
    for (int b = 0; b < 32; b++) g_zp[((size_t)kc * BB + b) * NZ + j] = acc[b];
}

// ---------------------------------------------------------------------------
// K5: sum z partials + bias, gates -> h_new/c_new (fp32 out).
// grid 128 = 32 b x 4 jq; coalesced partial reads.
// out: mel[0,2560) h[2560,35328) c[35328,68096)
// ---------------------------------------------------------------------------
__global__ __launch_bounds__(256) void k_gates(const float* __restrict__ bias,
                                               const float* __restrict__ c,
                                               float* __restrict__ out) {
    int b = blockIdx.x >> 2, jq = blockIdx.x & 3;
    int j = jq * 256 + threadIdx.x;
    float zi = bias[j], zf = bias[1024 + j], zg = bias[2048 + j], zo = bias[3072 + j];
#pragma unroll 4
    for (int kc = 0; kc < KC; kc++) {
        const float* zp = g_zp + ((size_t)kc * BB + b) * NZ;
        zi += zp[j];
        zf += zp[1024 + j];
        zg += zp[2048 + j];
        zo += zp[3072 + j];
    }
    int idx = b * 1024 + j;
    float cn = sigmoid_fast(zf) * c[idx] + sigmoid_fast(zi) * tanh_fast(zg);
    float hn = sigmoid_fast(zo) * tanh_fast(cn);
    g_hn[idx] = hn;
    out[2560 + idx] = hn;
    out[35328 + idx] = cn;
}

// ---------------------------------------------------------------------------
// K6: mel[b,m] = h_new[b,:] @ proj_w[:,m] + proj_b[m]
// grid 32; 160 active threads = 80 m x 2 d-halves, LDS combine.
// ---------------------------------------------------------------------------
__global__ __launch_bounds__(256) void k_proj(const float* __restrict__ pw,
                                              const float* __restrict__ pb,
                                              float* __restrict__ out) {
    __shared__ float lh[1024];
    __shared__ float pacc[2][MELD];
    int b = blockIdx.x, tid = threadIdx.x;
    for (int i = tid; i < 1024; i += 256) lh[i] = g_hn[b * 1024 + i];
    __syncthreads();
    int m = tid & 127;
    int g = tid >> 7;
    if (m < MELD) {
        float acc = 0.f;
        int d0 = g * 512;
#pragma unroll 8
        for (int d = d0; d < d0 + 512; d++) acc = fmaf(lh[d], pw[d * MELD + m], acc);
        pacc[g][m] = acc;
    }
    __syncthreads();
    if (tid < MELD) out[b * MELD + tid] = pacc[0][tid] + pacc[1][tid] + pb[tid];
}

extern "C" void kernel_launch(void* const* d_in, const int* in_sizes, int n_in,
                              void* d_out, int out_size, void* d_ws, size_t ws_size,
                              hipStream_t stream) {
    const float* pm   = (const float*)d_in[0];   // prev_mel_frame [32,80]
    const float* enc  = (const float*)d_in[1];   // encoder_outputs [32,1024,1024]
    const float* h    = (const float*)d_in[2];   // h [32,1024]
    const float* c    = (const float*)d_in[3];   // c [32,1024]
    const float* asc  = (const float*)d_in[4];   // attn_scale [1024]
    const float* kern = (const float*)d_in[5];   // kernel [1104,4096]
    const float* reck = (const float*)d_in[6];   // rec_kernel [1024,4096]
    const float* bias = (const float*)d_in[7];   // bias [4096]
    const float* pw   = (const float*)d_in[8];   // proj_w [1024,80]
    const float* pb   = (const float*)d_in[9];   // proj_b [80]
    float* out = (float*)d_out;                  // fp32: mel | h_new | c_new

    k_scores <<<8192, 256, 0, stream>>>(enc, h, asc);
    k_context<<<dim3(32, 8), 256, 0, stream>>>(enc);
    k_ctxsum <<<128, 256, 0, stream>>>();
    k_zmm    <<<544, 256, 0, stream>>>(pm, h, kern, reck);
    k_gates  <<<128, 256, 0, stream>>>(bias, c, out);
    k_proj   <<<32, 256, 0, stream>>>(pw, pb, out);
}